// Round 8
// baseline (61.048 us; speedup 1.0000x reference)
//
#include <hip/hip_runtime.h>
#include <hip/hip_bf16.h>

#define NEG 0.2f
#define LOG2E 1.4426950408889634f

typedef __attribute__((ext_vector_type(8))) short bf16x8;
typedef __attribute__((ext_vector_type(4))) float f32x4;
typedef __attribute__((ext_vector_type(16))) float f32x16;
typedef __attribute__((ext_vector_type(4))) int int4v;
typedef __attribute__((ext_vector_type(2))) int int2v;

__device__ __forceinline__ float lrelu(float t){ return fmaxf(t, NEG * t); }
__device__ __forceinline__ float fast_exp2(float x){
  float r; asm("v_exp_f32 %0, %1" : "=v"(r) : "v"(x)); return r;
}
__device__ __forceinline__ unsigned short f2bf(float f){   // RNE
  union { float f; unsigned int u; } v; v.f = f;
  unsigned int r = v.u + 0x7FFFu + ((v.u >> 16) & 1u);
  return (unsigned short)(r >> 16);
}

// ---------------- K0: Wt[o][k] = bf16(W[k][o]), once ----------------
__global__ __launch_bounds__(256) void k0_wt(const float* __restrict__ W,
                                             unsigned short* __restrict__ Wt){
  __shared__ __align__(16) unsigned short wl[128*136];
  const int t = threadIdx.x;
  {
    const int k = t >> 1, oh = (t & 1) * 64;
#pragma unroll 8
    for (int e = 0; e < 64; ++e)
      wl[(oh + e)*136 + k] = f2bf(W[k*128 + oh + e]);
  }
  __syncthreads();
  {
    const int o = t >> 1, ks = (t & 1) * 64;
#pragma unroll
    for (int g = 0; g < 8; ++g){
      int4v v = *(const int4v*)(wl + o*136 + ks + g*8);
      *(int4v*)(Wt + o*128 + ks + g*8) = v;
    }
  }
}

// ---------------- K1: h^T via MFMA + scaled s_src/s_dst + ht store ----------------
__global__ __launch_bounds__(256) void k1_fused(const float* __restrict__ x,
                                                const unsigned short* __restrict__ Wt,
                                                const float* __restrict__ a,
                                                unsigned short* __restrict__ ht,
                                                float* __restrict__ ssrcL,
                                                float* __restrict__ sdstL){
  __shared__ __align__(16) unsigned short wtl[128*136];
  __shared__ __align__(16) unsigned short xl[32*136];
  __shared__ __align__(16) unsigned short tlw[128*34];
  __shared__ float sred[2][4][2][16];
  const int t = threadIdx.x;
  const int bx = blockIdx.x;                 // b*64 + jt
  const int b  = bx >> 6;
  const int jt = bx & 63;
  const long rowbase = (long)bx * 32;
  {
    const int o = t >> 1, seg = (t & 1) * 64;
    const int4v* src = (const int4v*)(Wt + o*128 + seg);
    int4v* dst = (int4v*)(wtl + o*136 + seg);
#pragma unroll
    for (int g = 0; g < 8; ++g) dst[g] = src[g];
  }
  {
    const int i = t >> 3, ks = (t & 7) * 16;
    const f32x4* src = (const f32x4*)(x + (rowbase + i)*128 + ks);
    unsigned int q[8];
#pragma unroll
    for (int g = 0; g < 4; ++g){
      f32x4 v = src[g];
      q[g*2]   = (unsigned)f2bf(v[0]) | ((unsigned)f2bf(v[1]) << 16);
      q[g*2+1] = (unsigned)f2bf(v[2]) | ((unsigned)f2bf(v[3]) << 16);
    }
    int4v* dst = (int4v*)(xl + i*136 + ks);
    dst[0] = *(int4v*)&q[0];
    dst[1] = *(int4v*)&q[4];
  }
  __syncthreads();
  const int w = t >> 6, lane = t & 63, lr = lane & 15, hi = lane >> 4;
  f32x4 zro = {0.f, 0.f, 0.f, 0.f};
  f32x4 acc00 = zro, acc01 = zro, acc10 = zro, acc11 = zro;
#pragma unroll
  for (int ks = 0; ks < 4; ++ks){
    const bf16x8 a0 = *(const bf16x8*)(wtl + (w*32      + lr)*136 + ks*32 + hi*8);
    const bf16x8 a1 = *(const bf16x8*)(wtl + (w*32 + 16 + lr)*136 + ks*32 + hi*8);
    const bf16x8 b0 = *(const bf16x8*)(xl + (     lr)*136 + ks*32 + hi*8);
    const bf16x8 b1 = *(const bf16x8*)(xl + (16 + lr)*136 + ks*32 + hi*8);
    acc00 = __builtin_amdgcn_mfma_f32_16x16x32_bf16(a0, b0, acc00, 0, 0, 0);
    acc01 = __builtin_amdgcn_mfma_f32_16x16x32_bf16(a0, b1, acc01, 0, 0, 0);
    acc10 = __builtin_amdgcn_mfma_f32_16x16x32_bf16(a1, b0, acc10, 0, 0, 0);
    acc11 = __builtin_amdgcn_mfma_f32_16x16x32_bf16(a1, b1, acc11, 0, 0, 0);
  }
  {
    const f32x4 as0 = *(const f32x4*)(a +       w*32      + hi*4);
    const f32x4 as1 = *(const f32x4*)(a +       w*32 + 16 + hi*4);
    const f32x4 ad0 = *(const f32x4*)(a + 128 + w*32      + hi*4);
    const f32x4 ad1 = *(const f32x4*)(a + 128 + w*32 + 16 + hi*4);
    float ps0, ps1, pd0, pd1;
    {
      f32x4 u = acc00*as0 + acc10*as1;  ps0 = u[0]+u[1]+u[2]+u[3];
      f32x4 v = acc01*as0 + acc11*as1;  ps1 = v[0]+v[1]+v[2]+v[3];
      f32x4 p = acc00*ad0 + acc10*ad1;  pd0 = p[0]+p[1]+p[2]+p[3];
      f32x4 r = acc01*ad0 + acc11*ad1;  pd1 = r[0]+r[1]+r[2]+r[3];
    }
#pragma unroll
    for (int off = 16; off <= 32; off <<= 1){
      ps0 += __shfl_xor(ps0, off); ps1 += __shfl_xor(ps1, off);
      pd0 += __shfl_xor(pd0, off); pd1 += __shfl_xor(pd1, off);
    }
    if (hi == 0){
      sred[0][w][0][lr] = ps0; sred[0][w][1][lr] = ps1;
      sred[1][w][0][lr] = pd0; sred[1][w][1][lr] = pd1;
    }
  }
#pragma unroll
  for (int q = 0; q < 4; ++q){
    tlw[(w*32      + hi*4 + q)*34      + lr] = f2bf(acc00[q]);
    tlw[(w*32      + hi*4 + q)*34 + 16 + lr] = f2bf(acc01[q]);
    tlw[(w*32 + 16 + hi*4 + q)*34      + lr] = f2bf(acc10[q]);
    tlw[(w*32 + 16 + hi*4 + q)*34 + 16 + lr] = f2bf(acc11[q]);
  }
  __syncthreads();
  {
    const int o = t >> 1, jseg = (t & 1) * 16;
    const unsigned int* src = (const unsigned int*)(tlw + o*34 + jseg);
    unsigned int p[8];
#pragma unroll
    for (int g = 0; g < 8; ++g) p[g] = src[g];
    unsigned short* dst = ht + (long)b*262144 + (long)o*2048 + jt*32 + jseg;
    ((int4v*)dst)[0] = *(int4v*)&p[0];
    ((int4v*)dst)[1] = *(int4v*)&p[4];
  }
  if (t < 64){
    const int sel = t >> 5, jl = t & 31;
    const int ig = jl >> 4, l2 = jl & 15;
    const float s = sred[sel][0][ig][l2] + sred[sel][1][ig][l2]
                  + sred[sel][2][ig][l2] + sred[sel][3][ig][l2];
    if (sel == 0) ssrcL[rowbase + jl] = s * LOG2E;
    else          sdstL[rowbase + jl] = s * LOG2E;
  }
}

// ---------------- K2a: per-batch max of sdstL (ONE scalar per batch) ----------------
__global__ __launch_bounds__(256) void k2_max(const float* __restrict__ sdstL,
                                              float* __restrict__ M){
  __shared__ float red[4];
  const int b = blockIdx.x, t = threadIdx.x;
  const int lane = t & 63, w = t >> 6;
  const f32x4* sd = (const f32x4*)(sdstL + (long)b*2048 + t*8);
  f32x4 v0 = sd[0], v1 = sd[1];
  float mx = fmaxf(fmaxf(fmaxf(v0[0], v0[1]), fmaxf(v0[2], v0[3])),
                   fmaxf(fmaxf(v1[0], v1[1]), fmaxf(v1[2], v1[3])));
#pragma unroll
  for (int off = 1; off <= 32; off <<= 1) mx = fmaxf(mx, __shfl_xor(mx, off));
  if (lane == 0) red[w] = mx;
  __syncthreads();
  if (t == 0) M[b] = fmaxf(fmaxf(red[0], red[1]), fmaxf(red[2], red[3]));
}

// ---------------- K2b: per-row C_i = m_L + log2(sum_j 2^(lrelu(siL+sjL)-m_L)) ----------------
__global__ __launch_bounds__(256) void k2_ml(const float* __restrict__ ssrcL,
                                             const float* __restrict__ sdstL,
                                             const float* __restrict__ M,
                                             float* __restrict__ carr){
  const int lane = threadIdx.x & 63;
  const long row = (long)blockIdx.x * 4 + (threadIdx.x >> 6);
  const int b = (int)(row >> 11);
  const float siL = ssrcL[row];
  const float mL = lrelu(siL + M[b]);
  const float* sd = sdstL + (long)b*2048;
  float sum = 0.f;
#pragma unroll
  for (int k = 0; k < 8; ++k){
    f32x4 v = *(const f32x4*)(sd + lane*4 + k*256);
#pragma unroll
    for (int e = 0; e < 4; ++e) sum += fast_exp2(lrelu(siL + v[e]) - mL);
  }
#pragma unroll
  for (int off = 1; off <= 32; off <<= 1) sum += __shfl_xor(sum, off);
  if (lane == 0) carr[row] = mL + __log2f(sum);
}

// ---------------- K3: out = LR( (adj + alpha) @ h ), 8-wave cooperative ----------------
// grid 512 = 8b x 64 tiles (BM=32, XCD-swizzled); block 512 = 8 waves =
// (4 col-groups cg) x (2 K-subhalves sh). Per BK=64 step each wave: stages its
// 32 private ht rows / 32-j subhalf via global_load_lds (linear dest, source
// pre-swizzled ^(row&3)); computes 4 weights/lane into shared XOR-swizzled
// wtile; 2 MFMA 32x32x16. One barrier/step, counted vmcnt(4) -> next-step
// stage + adj refill stay in flight. Epilogue adds the two K-half partials.
__global__ __launch_bounds__(512, 4) void k3_main(const float* __restrict__ adj,
                                                  const unsigned short* __restrict__ ht,
                                                  const float* __restrict__ ssrcL,
                                                  const float* __restrict__ sdstL,
                                                  const float* __restrict__ carr,
                                                  float* __restrict__ out){
  __shared__ __align__(16) char smem[40960];
  // httile[buf][sh][row 128][j 32] bf16 = 32 KB; wtile[buf][row 32][j 64] bf16 = 8 KB
  unsigned short (*httile)[2][128][32] = (unsigned short (*)[2][128][32])smem;
  unsigned short (*wtile)[32][64]      = (unsigned short (*)[32][64])(smem + 32768);
  float* red = (float*)smem;                       // 16 KB epilogue (aliases buf0)
  const int t    = threadIdx.x;
  const int bxr  = blockIdx.x;
  const int bx   = ((bxr & 7) << 6) | (bxr >> 3);  // batch -> one XCD
  const int b    = bx >> 6;
  const int i0   = (bx & 63) * 32;
  const int w    = t >> 6, lane = t & 63;
  const int cg   = w & 3, sh = w >> 2;
  const int r32  = lane & 31, hl = lane >> 5;
  const int r7   = r32 & 7;
  const long rowg = (long)b*2048 + i0 + r32;
  const float siL = ssrcL[rowg];
  const float Ci  = carr[rowg];
  const float* adjL = adj + rowg*2048 + w*8 + hl*4;     // this lane's 4-j weight slice
  const float* sdbL = sdstL + (long)b*2048 + w*8 + hl*4;
  // staging source: lane l -> row (cg*32 + (l>>2)), physical chunk (l&3) holds
  // logical j-chunk (l&3)^(row&3)  [rule #21: linear dest + pre-swizzled src]
  const unsigned short* sgbase = ht + (long)b*262144
                               + (long)(cg*32 + (lane >> 2))*2048 + sh*32
                               + (((lane & 3) ^ ((lane >> 2) & 3))) * 8;

  f32x16 acc;
#pragma unroll
  for (int e = 0; e < 16; ++e) acc[e] = 0.f;
  f32x4 avA, dvA, avB, dvB;

  // ---- prologue: stage window 0 -> buf0; adj/sd sets for windows 0,1 ----
#pragma unroll
  for (int rr = 0; rr < 2; ++rr)
    __builtin_amdgcn_global_load_lds(
      (const __attribute__((address_space(1))) void*)(sgbase + rr*32768),
      (__attribute__((address_space(3))) void*)&httile[0][sh][cg*32 + rr*16][0], 16, 0, 0);
  avA = *(const f32x4*)(adjL);      dvA = *(const f32x4*)(sdbL);
  avB = *(const f32x4*)(adjL + 64); dvB = *(const f32x4*)(sdbL + 64);

#define K3_STEP(KT, BUF, DO_STAGE, DO_REFILL, VMSTR, AV, DV) do{                 \
    if (DO_STAGE){                                                               \
      _Pragma("unroll")                                                          \
      for (int rr = 0; rr < 2; ++rr)                                             \
        __builtin_amdgcn_global_load_lds(                                        \
          (const __attribute__((address_space(1))) void*)(sgbase + ((KT)+1)*64 + rr*32768), \
          (__attribute__((address_space(3))) void*)&httile[(BUF)^1][sh][cg*32 + rr*16][0], 16, 0, 0); \
    }                                                                            \
    {  float wv[4];                                                              \
       _Pragma("unroll")                                                         \
       for (int e = 0; e < 4; ++e)                                               \
         wv[e] = AV[e] + fast_exp2(lrelu(siL + DV[e]) - Ci);                     \
       const unsigned p01 = __builtin_amdgcn_perm(__float_as_uint(wv[1]), __float_as_uint(wv[0]), 0x07060302u); \
       const unsigned p23 = __builtin_amdgcn_perm(__float_as_uint(wv[3]), __float_as_uint(wv[2]), 0x07060302u); \
       int2v iv = {(int)p01, (int)p23};                                          \
       *(int2v*)&wtile[BUF][r32][(w ^ r7)*8 + hl*4] = iv;                        \
    }                                                                            \
    if (DO_REFILL){                                                              \
      AV = *(const f32x4*)(adjL + ((KT)+2)*64);                                  \
      DV = *(const f32x4*)(sdbL + ((KT)+2)*64);                                  \
    }                                                                            \
    asm volatile("s_waitcnt vmcnt(" VMSTR ") lgkmcnt(0)" ::: "memory");          \
    __builtin_amdgcn_sched_barrier(0);                                           \
    __builtin_amdgcn_s_barrier();                                                \
    __builtin_amdgcn_sched_barrier(0);                                           \
    __builtin_amdgcn_s_setprio(1);                                               \
    _Pragma("unroll")                                                            \
    for (int g = 0; g < 2; ++g){                                                 \
      const bf16x8 afr = *(const bf16x8*)&wtile[BUF][r32][((sh*4 + g*2 + hl) ^ r7)*8]; \
      const bf16x8 bfr = *(const bf16x8*)&httile[BUF][sh][cg*32 + r32][((g*2 + hl) ^ (r32 & 3))*8]; \
      acc = __builtin_amdgcn_mfma_f32_32x32x16_bf16(afr, bfr, acc, 0, 0, 0);     \
    }                                                                            \
    __builtin_amdgcn_s_setprio(0);                                               \
    __builtin_amdgcn_sched_barrier(0);                                           \
  }while(0)

  for (int kt = 0; kt < 30; kt += 2){
    K3_STEP(kt,     0, 1, 1, "4", avA, dvA);
    K3_STEP(kt + 1, 1, 1, 1, "4", avB, dvB);
  }
  K3_STEP(30, 0, 1, 0, "4", avA, dvA);
  K3_STEP(31, 1, 0, 0, "0", avB, dvB);
#undef K3_STEP

  // ---- epilogue: add K-half partials (red aliases buf0; step-31 read buf1) ----
  if (sh == 1){
#pragma unroll
    for (int rg = 0; rg < 16; ++rg){
      const int rr = (rg & 3) + 8*(rg >> 2) + 4*hl;
      red[cg*1024 + rr*32 + r32] = acc[rg];
    }
  }
  __syncthreads();
  if (sh == 0){
#pragma unroll
    for (int rg = 0; rg < 16; ++rg){
      const int rr = (rg & 3) + 8*(rg >> 2) + 4*hl;
      const float v = acc[rg] + red[cg*1024 + rr*32 + r32];
      out[((long)b*2048 + i0 + rr)*128 + cg*32 + r32] = lrelu(v);
    }
  }
}

extern "C" void kernel_launch(void* const* d_in, const int* in_sizes, int n_in,
                              void* d_out, int out_size, void* d_ws, size_t ws_size,
                              hipStream_t stream){
  const float* x   = (const float*)d_in[0];
  const float* adj = (const float*)d_in[1];
  const float* W   = (const float*)d_in[2];
  const float* a   = (const float*)d_in[3];
  float* out = (float*)d_out;
  char* ws = (char*)d_ws;

  unsigned short* ht    = (unsigned short*)(ws);              // 4 MB
  float*          ssrcL = (float*)(ws + 4194304);             // 64 KB
  float*          sdstL = (float*)(ws + 4259840);             // 64 KB
  float*          carr  = (float*)(ws + 4325376);             // 64 KB
  unsigned short* Wt    = (unsigned short*)(ws + 4390912);    // 32 KB
  float*          M     = (float*)(ws + 4423680);             // 32 B

  k0_wt   <<<1,    256, 0, stream>>>(W, Wt);
  k1_fused<<<512,  256, 0, stream>>>(x, Wt, a, ht, ssrcL, sdstL);
  k2_max  <<<8,    256, 0, stream>>>(sdstL, M);
  k2_ml   <<<4096, 256, 0, stream>>>(ssrcL, sdstL, M, carr);
  k3_main <<<512,  512, 0, stream>>>(adj, ht, ssrcL, sdstL, carr, out);
}

// Round 9
// 56.585 us; speedup vs baseline: 1.0789x; 1.0789x over previous
//
#include <hip/hip_runtime.h>
#include <hip/hip_bf16.h>

#define NEG 0.2f
#define LOG2E 1.4426950408889634f

typedef __attribute__((ext_vector_type(8))) short bf16x8;
typedef __attribute__((ext_vector_type(4))) float f32x4;
typedef __attribute__((ext_vector_type(16))) float f32x16;
typedef __attribute__((ext_vector_type(4))) int int4v;

__device__ __forceinline__ float lrelu(float t){ return fmaxf(t, NEG * t); }
__device__ __forceinline__ float fast_exp2(float x){
  float r; asm("v_exp_f32 %0, %1" : "=v"(r) : "v"(x)); return r;
}
__device__ __forceinline__ unsigned short f2bf(float f){   // RNE
  union { float f; unsigned int u; } v; v.f = f;
  unsigned int r = v.u + 0x7FFFu + ((v.u >> 16) & 1u);
  return (unsigned short)(r >> 16);
}

// ---------------- K0: Wt[o][k] = bf16(W[k][o]), once ----------------
__global__ __launch_bounds__(256) void k0_wt(const float* __restrict__ W,
                                             unsigned short* __restrict__ Wt){
  __shared__ __align__(16) unsigned short wl[128*136];
  const int t = threadIdx.x;
  {
    const int k = t >> 1, oh = (t & 1) * 64;
#pragma unroll 8
    for (int e = 0; e < 64; ++e)
      wl[(oh + e)*136 + k] = f2bf(W[k*128 + oh + e]);
  }
  __syncthreads();
  {
    const int o = t >> 1, ks = (t & 1) * 64;
#pragma unroll
    for (int g = 0; g < 8; ++g){
      int4v v = *(const int4v*)(wl + o*136 + ks + g*8);
      *(int4v*)(Wt + o*128 + ks + g*8) = v;
    }
  }
}

// ---------------- K1: h^T via MFMA + scaled s_src/s_dst + ht store ----------------
__global__ __launch_bounds__(256) void k1_fused(const float* __restrict__ x,
                                                const unsigned short* __restrict__ Wt,
                                                const float* __restrict__ a,
                                                unsigned short* __restrict__ ht,
                                                float* __restrict__ ssrcL,
                                                float* __restrict__ sdstL){
  __shared__ __align__(16) unsigned short wtl[128*136];
  __shared__ __align__(16) unsigned short xl[32*136];
  __shared__ __align__(16) unsigned short tlw[128*34];
  __shared__ float sred[2][4][2][16];
  const int t = threadIdx.x;
  const int bx = blockIdx.x;                 // b*64 + jt
  const int b  = bx >> 6;
  const int jt = bx & 63;
  const long rowbase = (long)bx * 32;
  {
    const int o = t >> 1, seg = (t & 1) * 64;
    const int4v* src = (const int4v*)(Wt + o*128 + seg);
    int4v* dst = (int4v*)(wtl + o*136 + seg);
#pragma unroll
    for (int g = 0; g < 8; ++g) dst[g] = src[g];
  }
  {
    const int i = t >> 3, ks = (t & 7) * 16;
    const f32x4* src = (const f32x4*)(x + (rowbase + i)*128 + ks);
    unsigned int q[8];
#pragma unroll
    for (int g = 0; g < 4; ++g){
      f32x4 v = src[g];
      q[g*2]   = (unsigned)f2bf(v[0]) | ((unsigned)f2bf(v[1]) << 16);
      q[g*2+1] = (unsigned)f2bf(v[2]) | ((unsigned)f2bf(v[3]) << 16);
    }
    int4v* dst = (int4v*)(xl + i*136 + ks);
    dst[0] = *(int4v*)&q[0];
    dst[1] = *(int4v*)&q[4];
  }
  __syncthreads();
  const int w = t >> 6, lane = t & 63, lr = lane & 15, hi = lane >> 4;
  f32x4 zro = {0.f, 0.f, 0.f, 0.f};
  f32x4 acc00 = zro, acc01 = zro, acc10 = zro, acc11 = zro;
#pragma unroll
  for (int ks = 0; ks < 4; ++ks){
    const bf16x8 a0 = *(const bf16x8*)(wtl + (w*32      + lr)*136 + ks*32 + hi*8);
    const bf16x8 a1 = *(const bf16x8*)(wtl + (w*32 + 16 + lr)*136 + ks*32 + hi*8);
    const bf16x8 b0 = *(const bf16x8*)(xl + (     lr)*136 + ks*32 + hi*8);
    const bf16x8 b1 = *(const bf16x8*)(xl + (16 + lr)*136 + ks*32 + hi*8);
    acc00 = __builtin_amdgcn_mfma_f32_16x16x32_bf16(a0, b0, acc00, 0, 0, 0);
    acc01 = __builtin_amdgcn_mfma_f32_16x16x32_bf16(a0, b1, acc01, 0, 0, 0);
    acc10 = __builtin_amdgcn_mfma_f32_16x16x32_bf16(a1, b0, acc10, 0, 0, 0);
    acc11 = __builtin_amdgcn_mfma_f32_16x16x32_bf16(a1, b1, acc11, 0, 0, 0);
  }
  {
    const f32x4 as0 = *(const f32x4*)(a +       w*32      + hi*4);
    const f32x4 as1 = *(const f32x4*)(a +       w*32 + 16 + hi*4);
    const f32x4 ad0 = *(const f32x4*)(a + 128 + w*32      + hi*4);
    const f32x4 ad1 = *(const f32x4*)(a + 128 + w*32 + 16 + hi*4);
    float ps0, ps1, pd0, pd1;
    {
      f32x4 u = acc00*as0 + acc10*as1;  ps0 = u[0]+u[1]+u[2]+u[3];
      f32x4 v = acc01*as0 + acc11*as1;  ps1 = v[0]+v[1]+v[2]+v[3];
      f32x4 p = acc00*ad0 + acc10*ad1;  pd0 = p[0]+p[1]+p[2]+p[3];
      f32x4 r = acc01*ad0 + acc11*ad1;  pd1 = r[0]+r[1]+r[2]+r[3];
    }
#pragma unroll
    for (int off = 16; off <= 32; off <<= 1){
      ps0 += __shfl_xor(ps0, off); ps1 += __shfl_xor(ps1, off);
      pd0 += __shfl_xor(pd0, off); pd1 += __shfl_xor(pd1, off);
    }
    if (hi == 0){
      sred[0][w][0][lr] = ps0; sred[0][w][1][lr] = ps1;
      sred[1][w][0][lr] = pd0; sred[1][w][1][lr] = pd1;
    }
  }
#pragma unroll
  for (int q = 0; q < 4; ++q){
    tlw[(w*32      + hi*4 + q)*34      + lr] = f2bf(acc00[q]);
    tlw[(w*32      + hi*4 + q)*34 + 16 + lr] = f2bf(acc01[q]);
    tlw[(w*32 + 16 + hi*4 + q)*34      + lr] = f2bf(acc10[q]);
    tlw[(w*32 + 16 + hi*4 + q)*34 + 16 + lr] = f2bf(acc11[q]);
  }
  __syncthreads();
  {
    const int o = t >> 1, jseg = (t & 1) * 16;
    const unsigned int* src = (const unsigned int*)(tlw + o*34 + jseg);
    unsigned int p[8];
#pragma unroll
    for (int g = 0; g < 8; ++g) p[g] = src[g];
    unsigned short* dst = ht + (long)b*262144 + (long)o*2048 + jt*32 + jseg;
    ((int4v*)dst)[0] = *(int4v*)&p[0];
    ((int4v*)dst)[1] = *(int4v*)&p[4];
  }
  if (t < 64){
    const int sel = t >> 5, jl = t & 31;
    const int ig = jl >> 4, l2 = jl & 15;
    const float s = sred[sel][0][ig][l2] + sred[sel][1][ig][l2]
                  + sred[sel][2][ig][l2] + sred[sel][3][ig][l2];
    if (sel == 0) ssrcL[rowbase + jl] = s * LOG2E;
    else          sdstL[rowbase + jl] = s * LOG2E;
  }
}

// ---------------- K2a: per-batch max of sdstL ----------------
__global__ __launch_bounds__(256) void k2_max(const float* __restrict__ sdstL,
                                              float* __restrict__ M){
  __shared__ float red[4];
  const int b = blockIdx.x, t = threadIdx.x;
  const int lane = t & 63, w = t >> 6;
  const f32x4* sd = (const f32x4*)(sdstL + (long)b*2048 + t*8);
  f32x4 v0 = sd[0], v1 = sd[1];
  float mx = fmaxf(fmaxf(fmaxf(v0[0], v0[1]), fmaxf(v0[2], v0[3])),
                   fmaxf(fmaxf(v1[0], v1[1]), fmaxf(v1[2], v1[3])));
#pragma unroll
  for (int off = 1; off <= 32; off <<= 1) mx = fmaxf(mx, __shfl_xor(mx, off));
  if (lane == 0) red[w] = mx;
  __syncthreads();
  if (t == 0) M[b] = fmaxf(fmaxf(red[0], red[1]), fmaxf(red[2], red[3]));
}

// ---------------- K2b: per-row C_i = m_L + log2(sum_j 2^(lrelu(siL+sjL)-m_L)) ----------------
__global__ __launch_bounds__(256) void k2_ml(const float* __restrict__ ssrcL,
                                             const float* __restrict__ sdstL,
                                             const float* __restrict__ M,
                                             float* __restrict__ carr){
  const int lane = threadIdx.x & 63;
  const long row = (long)blockIdx.x * 4 + (threadIdx.x >> 6);
  const int b = (int)(row >> 11);
  const float siL = ssrcL[row];
  const float mL = lrelu(siL + M[b]);
  const float* sd = sdstL + (long)b*2048;
  float sum = 0.f;
#pragma unroll
  for (int k = 0; k < 8; ++k){
    f32x4 v = *(const f32x4*)(sd + lane*4 + k*256);
#pragma unroll
    for (int e = 0; e < 4; ++e) sum += fast_exp2(lrelu(siL + v[e]) - mL);
  }
#pragma unroll
  for (int off = 1; off <= 32; off <<= 1) sum += __shfl_xor(sum, off);
  if (lane == 0) carr[row] = mL + __log2f(sum);
}

// ---------------- K3: out = LR( (adj + alpha) @ h ), r7 structure, BK=128 ----------------
// grid 512 = 8b x 64 tiles (BM=32, XCD-swizzled); block 256 = 4 waves.
// Wave w owns output cols [w*32, w*32+32), FULL K. 16 steps of BK=128:
// wave stages its own 32 ht-rows x 128 j via global_load_lds (linear dest,
// source pre-XOR-swizzled span-16; rule #21); computes 16 weights/lane into
// shared XOR-swizzled wtile; 8 MFMA 32x32x16. ONE barrier/step, vmcnt(16)
// -> next-step stage + adj/sd refill stay in flight across the barrier.
__global__ __launch_bounds__(256, 2) void k3_main(const float* __restrict__ adj,
                                                  const unsigned short* __restrict__ ht,
                                                  const float* __restrict__ ssrcL,
                                                  const float* __restrict__ sdstL,
                                                  const float* __restrict__ carr,
                                                  float* __restrict__ out){
  __shared__ __align__(16) char smem[81920];
  unsigned short (*httile)[128][128] = (unsigned short (*)[128][128])smem;        // 2 x 32 KB
  unsigned short (*wtile)[32][128]   = (unsigned short (*)[32][128])(smem + 65536); // 2 x 8 KB
  const int t    = threadIdx.x;
  const int bxr  = blockIdx.x;
  const int bx   = ((bxr & 7) << 6) | (bxr >> 3);   // batch -> one XCD
  const int b    = bx >> 6;
  const int i0   = (bx & 63) * 32;
  const int w    = t >> 6, lane = t & 63;
  const int r32  = lane & 31, hl = lane >> 5;
  const int xr   = r32 & 15;
  const int c0   = w*4 + hl*2;                      // lane's first logical j-chunk
  const long rowg = (long)b*2048 + i0 + r32;
  const float siL = ssrcL[rowg];
  const float Ci  = carr[rowg];
  const float* adjL = adj + rowg*2048 + w*32 + hl*16;   // lane's 16-j weight slice
  const float* sdbL = sdstL + (long)b*2048 + w*32 + hl*16;
  // staging: instr ii covers rows w*32 + ii*4 + (lane>>4); phys chunk lane&15
  // holds logical chunk (lane&15) ^ ((ii*4 + (lane>>4)) & 15)
  const unsigned short* sgrow = ht + (long)b*262144 + (long)(w*32 + (lane >> 4))*2048;
  const int sch = (lane & 15) ^ (lane >> 4);

  f32x16 acc;
#pragma unroll
  for (int e = 0; e < 16; ++e) acc[e] = 0.f;
  f32x4 avA[4], dvA[4], avB[4], dvB[4];

#define K3_STAGE(B2, WIN) do{                                                    \
    _Pragma("unroll")                                                            \
    for (int ii = 0; ii < 8; ++ii){                                              \
      __builtin_amdgcn_global_load_lds(                                          \
        (const __attribute__((address_space(1))) void*)                          \
          (sgrow + (long)ii*8192 + (WIN) + (sch ^ ((ii*4) & 15))*8),             \
        (__attribute__((address_space(3))) void*)&httile[B2][w*32 + ii*4][0],    \
        16, 0, 0);                                                               \
    }                                                                            \
  }while(0)

#define K3_REFILL(AV, DV, WIN) do{                                               \
    _Pragma("unroll")                                                            \
    for (int g = 0; g < 4; ++g){                                                 \
      AV[g] = *(const f32x4*)(adjL + (WIN) + g*4);                               \
      DV[g] = *(const f32x4*)(sdbL + (WIN) + g*4);                               \
    }                                                                            \
  }while(0)

  // ---- prologue: stage tile0 -> buf0; adj/sd sets for steps 0,1 ----
  K3_STAGE(0, 0);
  K3_REFILL(avA, dvA, 0);
  K3_REFILL(avB, dvB, 128);
  asm volatile("s_waitcnt vmcnt(16)" ::: "memory");
  __builtin_amdgcn_sched_barrier(0);

#define K3_STEP(KT, BUF, DO_STAGE, DO_REFILL, VMSTR, AV, DV) do{                 \
    if (DO_STAGE) K3_STAGE((BUF)^1, ((KT)+1)*128);                               \
    {  unsigned pw[8];                                                           \
       _Pragma("unroll")                                                         \
       for (int g = 0; g < 4; ++g){                                              \
         float w0 = AV[g][0] + fast_exp2(lrelu(siL + DV[g][0]) - Ci);            \
         float w1 = AV[g][1] + fast_exp2(lrelu(siL + DV[g][1]) - Ci);            \
         float w2 = AV[g][2] + fast_exp2(lrelu(siL + DV[g][2]) - Ci);            \
         float w3 = AV[g][3] + fast_exp2(lrelu(siL + DV[g][3]) - Ci);            \
         pw[g*2]   = __builtin_amdgcn_perm(__float_as_uint(w1), __float_as_uint(w0), 0x07060302u); \
         pw[g*2+1] = __builtin_amdgcn_perm(__float_as_uint(w3), __float_as_uint(w2), 0x07060302u); \
       }                                                                         \
       int4v iv0 = {(int)pw[0], (int)pw[1], (int)pw[2], (int)pw[3]};             \
       int4v iv1 = {(int)pw[4], (int)pw[5], (int)pw[6], (int)pw[7]};             \
       *(int4v*)&wtile[BUF][r32][( c0      ^ xr)*8] = iv0;                       \
       *(int4v*)&wtile[BUF][r32][((c0 + 1) ^ xr)*8] = iv1;                       \
    }                                                                            \
    if (DO_REFILL) K3_REFILL(AV, DV, ((KT)+2)*128);                              \
    asm volatile("s_waitcnt vmcnt(" VMSTR ") lgkmcnt(0)" ::: "memory");          \
    __builtin_amdgcn_sched_barrier(0);                                           \
    __builtin_amdgcn_s_barrier();                                                \
    __builtin_amdgcn_sched_barrier(0);                                           \
    __builtin_amdgcn_s_setprio(1);                                               \
    _Pragma("unroll")                                                            \
    for (int g = 0; g < 8; ++g){                                                 \
      const int cp = ((g*2 + hl) ^ xr)*8;                                        \
      const bf16x8 afr = *(const bf16x8*)&wtile[BUF][r32][cp];                   \
      const bf16x8 bfr = *(const bf16x8*)&httile[BUF][w*32 + r32][cp];           \
      acc = __builtin_amdgcn_mfma_f32_32x32x16_bf16(afr, bfr, acc, 0, 0, 0);     \
    }                                                                            \
    __builtin_amdgcn_s_setprio(0);                                               \
    __builtin_amdgcn_sched_barrier(0);                                           \
  }while(0)

  for (int kt = 0; kt < 14; kt += 2){
    K3_STEP(kt,     0, 1, 1, "16", avA, dvA);
    K3_STEP(kt + 1, 1, 1, 1, "16", avB, dvB);
  }
  K3_STEP(14, 0, 1, 0, "16", avA, dvA);   // stages tile 15
  K3_STEP(15, 1, 0, 0, "0",  avB, dvB);   // final
#undef K3_STEP
#undef K3_STAGE
#undef K3_REFILL

  // ---- epilogue: direct store (full-K acc per wave) ----
#pragma unroll
  for (int rg = 0; rg < 16; ++rg){
    const int rr = (rg & 3) + 8*(rg >> 2) + 4*hl;
    out[((long)b*2048 + i0 + rr)*128 + w*32 + r32] = lrelu(acc[rg]);
  }
}

extern "C" void kernel_launch(void* const* d_in, const int* in_sizes, int n_in,
                              void* d_out, int out_size, void* d_ws, size_t ws_size,
                              hipStream_t stream){
  const float* x   = (const float*)d_in[0];
  const float* adj = (const float*)d_in[1];
  const float* W   = (const float*)d_in[2];
  const float* a   = (const float*)d_in[3];
  float* out = (float*)d_out;
  char* ws = (char*)d_ws;

  unsigned short* ht    = (unsigned short*)(ws);              // 4 MB
  float*          ssrcL = (float*)(ws + 4194304);             // 64 KB
  float*          sdstL = (float*)(ws + 4259840);             // 64 KB
  float*          carr  = (float*)(ws + 4325376);             // 64 KB
  unsigned short* Wt    = (unsigned short*)(ws + 4390912);    // 32 KB
  float*          M     = (float*)(ws + 4423680);             // 32 B

  k0_wt   <<<1,    256, 0, stream>>>(W, Wt);
  k1_fused<<<512,  256, 0, stream>>>(x, Wt, a, ht, ssrcL, sdstL);
  k2_max  <<<8,    256, 0, stream>>>(sdstL, M);
  k2_ml   <<<4096, 256, 0, stream>>>(ssrcL, sdstL, M, carr);
  k3_main <<<512,  256, 0, stream>>>(adj, ht, ssrcL, sdstL, carr, out);
}